// Round 3
// baseline (14385.335 us; speedup 1.0000x reference)
//
#include <hip/hip_runtime.h>
#include <hip/hip_bf16.h>

// QLSTM: SEQ=1024, B=64, D_IN=256, D_H=256, fp32 in/out.
// Phase 1: Xp = x @ Wx + bias  (f16 MFMA GEMM, no sequential dep) — unchanged.
// Phase 2: 64 recurrences split across 2 WGs each -> 128 WGs = 128 CUs (2x round-2).
//   WG (b, r): 512 threads, thread tid -> gate g=tid&3, h'=tid>>2, h=r*128+h',
//   col j = g*256+h. ONE col/thread => whole Wh column = 32 uint4 = 128 arch VGPRs.
//   No LDS weights, no AGPR shuffling (round-2 lesson: VGPR_Count=128 proved 2-col
//   mapping kept weights in AGPRs -> v_accvgpr_read per dot2, ~40% of VALU issue).
//   Gate combine: f,i,g,o live in 4 adjacent lanes -> 3x shfl_xor, no LDS roundtrip.
//   Cross-WG hx exchange per step via L2: data slots double-buffered by parity,
//   per-WG flag advanced by 64 release fetch_adds (RMWs extend the release sequence
//   => one acquire poll orders all 64 data words; no threadfence, no extra barrier).
//   Partner half staged into hxb[par^1] BEFORE the single per-step lds_barrier.
//   Co-residency: 128 WGs x 8 waves x ~176 regs = 1 WG/CU, 128 <= 256 CUs.
//   Pairing r=bid>>6: WGs (b, b+64) land on the same XCD under bid%8 placement.

typedef _Float16 f16;
typedef _Float16 f16x2 __attribute__((ext_vector_type(2)));
typedef _Float16 f16x4 __attribute__((ext_vector_type(4)));
typedef _Float16 f16x8 __attribute__((ext_vector_type(8)));
typedef float f32x4 __attribute__((ext_vector_type(4)));

#define SEQ 1024
#define BATCH 64
#define DIN 256
#define DH 256
#define NCOL 1024

// ---- ws layout (bytes) ----
#define WXP_OFF   0u                 // f16 [32][1024][8]
#define WHF_OFF   524288u            // f16 [1024 cols][256 rows]
#define BIAS_OFF  1048576u           // f32 [1024]
#define HXS_OFF   1052672u           // f16 [64][256]
#define CXS_OFF   1085440u           // f32 [64][256]
#define XCHG_OFF  1150976u           // u32 [64 b][2 r][2 par][64]  = 131072 B
#define FLAG_OFF  1282048u           // int [128] (+pad)
#define XP_OFF    1283072u           // f16 [Tc*64][1024]

__device__ __forceinline__ float dot2(unsigned int h, unsigned int w, float acc) {
#if __has_builtin(__builtin_amdgcn_fdot2)
  return __builtin_amdgcn_fdot2(__builtin_bit_cast(f16x2, h),
                                __builtin_bit_cast(f16x2, w), acc, false);
#else
  f16x2 a = __builtin_bit_cast(f16x2, h);
  f16x2 b = __builtin_bit_cast(f16x2, w);
  return acc + (float)a[0] * (float)b[0] + (float)a[1] * (float)b[1];
#endif
}

__device__ __forceinline__ float fast_sigmoid(float x) {
  float e = __expf(-x);
  return __builtin_amdgcn_rcpf(1.0f + e);
}
__device__ __forceinline__ float fast_tanh(float x) {
  x = fminf(fmaxf(x, -15.0f), 15.0f);
  float e = __expf(2.0f * x);
  return (e - 1.0f) * __builtin_amdgcn_rcpf(e + 1.0f);
}

// LDS-only barrier: does NOT drain vmcnt (out-store / Xp prefetch ride across).
__device__ __forceinline__ void lds_barrier() {
  asm volatile("s_waitcnt lgkmcnt(0)\n\ts_barrier" ::: "memory");
}

// ---------------- prep: convert / repack weights ----------------
__global__ void qlstm_prep(const float* __restrict__ Wf, const float* __restrict__ Wi,
                           const float* __restrict__ Wg, const float* __restrict__ Wo,
                           const float* __restrict__ bf_, const float* __restrict__ bi_,
                           const float* __restrict__ bg_, const float* __restrict__ bo_,
                           f16* __restrict__ Wxp, f16* __restrict__ WhF,
                           float* __restrict__ biasp, int* __restrict__ flags) {
  int tid = blockIdx.x * 256 + threadIdx.x;
  if (tid < 4 * 512 * 256) {
    int g = tid >> 17;
    int rem = tid & 131071;
    int k = rem >> 8, n = rem & 255;
    const float* W = (g == 0) ? Wf : (g == 1) ? Wi : (g == 2) ? Wg : Wo;
    float v = W[k * 256 + n];
    int j = (g << 8) + n;
    f16 hv = (f16)v;
    if (k < 256) {
      Wxp[((size_t)(k >> 3) * 1024 + j) * 8 + (k & 7)] = hv;
    } else {
      WhF[(size_t)j * 256 + (k - 256)] = hv;   // column-major per gate-col
    }
  }
  if (tid < 1024) {
    int g = tid >> 8, n = tid & 255;
    const float* bb = (g == 0) ? bf_ : (g == 1) ? bi_ : (g == 2) ? bg_ : bo_;
    biasp[tid] = bb[n];
  }
  if (tid < 128) flags[tid] = 0;   // exchange flags zeroed once per launch-replay
}

// ---------------- phase 1: Xp = x @ Wx + bias  (MFMA f16) ----------------
__global__ __launch_bounds__(256) void qlstm_xproj(
    const float* __restrict__ X, const f16* __restrict__ Wxp,
    const float* __restrict__ biasp, f16* __restrict__ Xp) {
  __shared__ f16 As[128][72];
  __shared__ f16 Bs[8 * 128 * 8];

  int tid = threadIdx.x;
  int tm = blockIdx.x, tn = blockIdx.y;
  int wave = tid >> 6, lane = tid & 63;
  int qm = (wave & 1) * 64, qn = (wave >> 1) * 64;
  int lm = lane & 15, lk = lane >> 4;

  f32x4 acc[4][4];
#pragma unroll
  for (int a = 0; a < 4; ++a)
#pragma unroll
    for (int b = 0; b < 4; ++b) acc[a][b] = (f32x4)0.0f;

  for (int k0 = 0; k0 < 256; k0 += 64) {
    {
      int r = tid >> 1, c0 = (tid & 1) * 32;
      const float4* src = (const float4*)(X + (size_t)(tm * 128 + r) * 256 + k0 + c0);
#pragma unroll
      for (int i = 0; i < 8; ++i) {
        float4 v = src[i];
        f16x4 pk = {(f16)v.x, (f16)v.y, (f16)v.z, (f16)v.w};
        *(f16x4*)&As[r][c0 + i * 4] = pk;
      }
    }
    {
#pragma unroll
      for (int it = 0; it < 4; ++it) {
        int idx = it * 256 + tid;
        int kgi = idx >> 7, n = idx & 127;
        ((uint4*)Bs)[idx] =
            *(const uint4*)(Wxp + (((size_t)(k0 >> 3) + kgi) * 1024 + tn * 128 + n) * 8);
      }
    }
    __syncthreads();
#pragma unroll
    for (int ks = 0; ks < 2; ++ks) {
      f16x8 af[4], bfr[4];
#pragma unroll
      for (int mi = 0; mi < 4; ++mi)
        af[mi] = *(const f16x8*)&As[qm + mi * 16 + lm][ks * 32 + lk * 8];
#pragma unroll
      for (int ni = 0; ni < 4; ++ni)
        bfr[ni] = *(const f16x8*)&Bs[(((ks * 4 + lk) * 128) + qn + ni * 16 + lm) * 8];
#pragma unroll
      for (int mi = 0; mi < 4; ++mi)
#pragma unroll
        for (int ni = 0; ni < 4; ++ni)
          acc[mi][ni] = __builtin_amdgcn_mfma_f32_16x16x32_f16(af[mi], bfr[ni],
                                                               acc[mi][ni], 0, 0, 0);
    }
    __syncthreads();
  }
  int m0 = tm * 128 + qm, j0 = tn * 128 + qn;
#pragma unroll
  for (int mi = 0; mi < 4; ++mi)
#pragma unroll
    for (int ni = 0; ni < 4; ++ni) {
      int j = j0 + ni * 16 + lm;
      float bv = biasp[j];
#pragma unroll
      for (int r = 0; r < 4; ++r) {
        int m = m0 + mi * 16 + lk * 4 + r;
        Xp[(size_t)m * 1024 + j] = (f16)(acc[mi][ni][r] + bv);
      }
    }
}

// ---------------- phase 2: sequential LSTM, 2 WGs per batch ----------------
__global__ __launch_bounds__(512)
__attribute__((amdgpu_waves_per_eu(2, 2))) void qlstm_seq(
    const f16* __restrict__ Xp, const f16* __restrict__ WhF,
    float* __restrict__ out, f16* __restrict__ hxs, float* __restrict__ cxs,
    float* __restrict__ hxout, float* __restrict__ cxout,
    unsigned* __restrict__ xchg, int* __restrict__ flags, int t0, int t1) {
  __shared__ f16 hxb[2][256];

  int tid = threadIdx.x;
  int lane = tid & 63;
  int bid = blockIdx.x;
  int b = bid & 63, r = bid >> 6;      // pair (b, b+64): same XCD under bid%8
  int g = tid & 3;                     // gate: 0=f 1=i 2=g 3=o
  int hh = tid >> 2;                   // 0..127
  int h = r * 128 + hh;
  int j = g * 256 + h;                 // my gate-column

  // whole Wh column in 32 uint4 = 128 arch VGPRs
  uint4 wr[32];
  {
    const uint4* q = (const uint4*)WhF + (size_t)j * 32;
#pragma unroll
    for (int c = 0; c < 32; ++c) wr[c] = q[c];
  }

  unsigned* hx32 = (unsigned*)hxb;

  float cx = 0.0f;
  int par0 = t0 & 1;
  if (t0 == 0) {
    if (tid < 128) hx32[tid] = 0u;                       // hxb[0][*]
  } else {
    if (tid < 128)
      hx32[par0 * 128 + tid] = ((const unsigned*)hxs)[b * 128 + tid];
    cx = cxs[b * 256 + h];            // quad-redundant (same h per quad)
  }

  f16 xa = Xp[(size_t)b * 1024 + j];

  int myflag = b * 2 + r;
  int pflag = b * 2 + (r ^ 1);
  unsigned* myslot = xchg + (size_t)(b * 2 + r) * 128;       // [2 par][64]
  unsigned* pslot = xchg + (size_t)(b * 2 + (r ^ 1)) * 128;

  __syncthreads();

  float hv = 0.0f;
  for (int t = t0; t < t1; ++t) {
    int par = t & 1;
    // full hx (own half written in-WG, partner half staged) -> lane-resident
    uint2 hA = *(const uint2*)(hxb[par] + lane * 4);

    float a = (float)xa;

    // prefetch next step's Xp (independent of recurrence; never drained in-loop)
    int tnx = (t + 1 < t1) ? (t + 1 - t0) : (t - t0);
    f16 xna = Xp[((size_t)tnx * BATCH + b) * 1024 + j];

    // 256 rows: 32 chunks x (4 readlane -> SGPR, 4 dot2 vs VGPR weights)
#pragma unroll
    for (int c = 0; c < 32; ++c) {
      unsigned s0 = (unsigned)__builtin_amdgcn_readlane((int)hA.x, 2 * c);
      unsigned s1 = (unsigned)__builtin_amdgcn_readlane((int)hA.y, 2 * c);
      unsigned s2 = (unsigned)__builtin_amdgcn_readlane((int)hA.x, 2 * c + 1);
      unsigned s3 = (unsigned)__builtin_amdgcn_readlane((int)hA.y, 2 * c + 1);
      a = dot2(s0, wr[c].x, a); a = dot2(s1, wr[c].y, a);
      a = dot2(s2, wr[c].z, a); a = dot2(s3, wr[c].w, a);
    }

    // gate combine across the quad (lanes 4h'+0..3): 3 shuffles, all lanes get all 4
    float q1 = __shfl_xor(a, 1, 64);
    float q2 = __shfl_xor(a, 2, 64);
    float q3 = __shfl_xor(q1, 2, 64);
    float vF = (g == 0) ? a : (g == 1) ? q1 : (g == 2) ? q2 : q3;
    float vI = (g == 1) ? a : (g == 0) ? q1 : (g == 3) ? q2 : q3;
    float vG = (g == 2) ? a : (g == 3) ? q1 : (g == 0) ? q2 : q3;
    float vO = (g == 3) ? a : (g == 2) ? q1 : (g == 1) ? q2 : q3;

    float f_ = fast_sigmoid(vF);
    float i_ = fast_sigmoid(vI);
    float g_ = fast_tanh(vG);
    float o_ = fast_sigmoid(vO);
    cx = fmaf(f_, cx, i_ * g_);        // quad-redundant, deterministic
    hv = o_ * fast_tanh(cx);

    f16 hv16 = (f16)hv;
    if (g == 0) hxb[par ^ 1][h] = hv16;

    // publish own half for partner's step t+1 (slot by parity, flag by 64 RMWs)
    float hvn = __shfl_down(hv, 4, 64);
    if ((tid & 7) == 0) {
      f16x2 pk = {hv16, (f16)hvn};
      __hip_atomic_store(&myslot[((t + 1) & 1) * 64 + (tid >> 3)],
                         __builtin_bit_cast(unsigned, pk),
                         __ATOMIC_RELAXED, __HIP_MEMORY_SCOPE_AGENT);
      __hip_atomic_fetch_add(&flags[myflag], 1, __ATOMIC_RELEASE,
                             __HIP_MEMORY_SCOPE_AGENT);
    }

    if (g == 0) out[((size_t)t * BATCH + b) * 256 + h] = hv;

    // stage partner half into hxb[par^1] (wave0 only; others wait at barrier)
    if (t + 1 < t1 && tid < 64) {
      int want = (t + 1) * 64;
      while (__hip_atomic_load(&flags[pflag], __ATOMIC_ACQUIRE,
                               __HIP_MEMORY_SCOPE_AGENT) < want)
        __builtin_amdgcn_s_sleep(1);
      unsigned v = __hip_atomic_load(&pslot[((t + 1) & 1) * 64 + tid],
                                     __ATOMIC_RELAXED, __HIP_MEMORY_SCOPE_AGENT);
      hx32[(par ^ 1) * 128 + (r ^ 1) * 64 + tid] = v;
    }
    lds_barrier();                     // single barrier per step, no vmcnt drain

    xa = xna;
  }

  if (g == 0) {
    hxs[b * 256 + h] = (f16)hv;        // own half; partner WG writes the other
    cxs[b * 256 + h] = cx;
    if (t1 == SEQ) {
      hxout[b * 256 + h] = hv;
      cxout[b * 256 + h] = cx;
    }
  }
}

extern "C" void kernel_launch(void* const* d_in, const int* in_sizes, int n_in,
                              void* d_out, int out_size, void* d_ws, size_t ws_size,
                              hipStream_t stream) {
  const float* X  = (const float*)d_in[0];
  const float* Wf = (const float*)d_in[1]; const float* bf_ = (const float*)d_in[2];
  const float* Wi = (const float*)d_in[3]; const float* bi_ = (const float*)d_in[4];
  const float* Wg = (const float*)d_in[5]; const float* bg_ = (const float*)d_in[6];
  const float* Wo = (const float*)d_in[7]; const float* bo_ = (const float*)d_in[8];
  float* out = (float*)d_out;

  char* ws = (char*)d_ws;
  f16*      Wxp   = (f16*)(ws + WXP_OFF);
  f16*      WhF   = (f16*)(ws + WHF_OFF);
  float*    biasp = (float*)(ws + BIAS_OFF);
  f16*      hxs   = (f16*)(ws + HXS_OFF);
  float*    cxs   = (float*)(ws + CXS_OFF);
  unsigned* xchg  = (unsigned*)(ws + XCHG_OFF);
  int*      flags = (int*)(ws + FLAG_OFF);
  f16*      Xp    = (f16*)(ws + XP_OFF);

  size_t avail = (ws_size > XP_OFF) ? (ws_size - XP_OFF) : 0;
  int Tc = SEQ;
  while (Tc > 2 && (size_t)Tc * BATCH * NCOL * 2 > avail) Tc >>= 1;

  qlstm_prep<<<2048, 256, 0, stream>>>(Wf, Wi, Wg, Wo, bf_, bi_, bg_, bo_,
                                       Wxp, WhF, biasp, flags);

  float* hxout = out + (size_t)SEQ * BATCH * DH;
  float* cxout = hxout + BATCH * DH;

  for (int t0 = 0; t0 < SEQ; t0 += Tc) {
    dim3 g1(Tc * BATCH / 128, NCOL / 128);
    qlstm_xproj<<<g1, 256, 0, stream>>>(X + (size_t)t0 * BATCH * DIN, Wxp, biasp, Xp);
    qlstm_seq<<<128, 512, 0, stream>>>(Xp, WhF, out, hxs, cxs,
                                       hxout, cxout, xchg, flags, t0, t0 + Tc);
  }
}

// Round 5
// 2092.770 us; speedup vs baseline: 6.8738x; 6.8738x over previous
//
#include <hip/hip_runtime.h>
#include <hip/hip_bf16.h>

// QLSTM: SEQ=1024, B=64, D_IN=256, D_H=256, fp32 in/out.
// Phase 1: Xp = x @ Wx + bias  (f16 MFMA GEMM, no sequential dep) — unchanged.
// Phase 2: 64 independent recurrences, 1 WG (512 thr, 8 waves, 2 waves/SIMD) per batch.
//   Gate pairing SAME-WAVE: wave w, lane l -> h = w*32 + (l&31), p = l>>5.
//   Gate exchange = 2x __shfl_xor(.,32); single raw lds_barrier per step (no vmcnt drain).
//   Wh rows 0..183 -> 184 regs, rows 184..255 -> LDS (144 KB), 2-deep pipelined.
// Round-3 lesson: cross-WG exchange fatal; recurrence must stay within one CU.
// Round-4 crashed with no GPU-side evidence (infra or pressure-asymmetric-branch issue);
//   the phase-stagger theory was never tested. This round re-runs it hardened:
//   both schedules use the SAME register set (A/B, 2-deep) and same macro counts.
// Theory: r2's 4240 cyc/step fits VALU(~1850)+DS(~1730)+tail(~650) ADDITIVELY -> zero
//   pipe overlap because the SIMD-partner waves {w, w+4} are phase-aligned (both stall
//   on lgkmcnt together; readlane->SGPR hazard nops have no partner to fill them).
//   Fix: stagger keyed on (wave>>2)&1 — waves 0-3 run the r2 order (DS phase early),
//   waves 4-7 run 13 pure-VGPR chunks first, DS interleave at the tail. While one wave
//   is DS-heavy its SIMD partner is pure-VALU -> pipes overlap.
//   Dual accumulators per column split the fdot2 dep chain 256 -> 64.

typedef _Float16 f16;
typedef _Float16 f16x2 __attribute__((ext_vector_type(2)));
typedef _Float16 f16x4 __attribute__((ext_vector_type(4)));
typedef _Float16 f16x8 __attribute__((ext_vector_type(8)));
typedef float f32x4 __attribute__((ext_vector_type(4)));

#define SEQ 1024
#define BATCH 64
#define DIN 256
#define DH 256
#define NCOL 1024
#define RV 184           // rows in VGPRs (23 chunks of 8)
#define RVC 23
#define RLC 9            // LDS chunks (72 rows)

// ---- ws layout (bytes) ----
#define WXP_OFF   0u                 // f16 [32][1024][8]
#define WHV_OFF   524288u            // f16 [1024 cols][184 rows]
#define WHL_OFF   901120u            // f16 [9][1024][8]
#define BIAS_OFF  1048576u           // f32 [1024]
#define HXS_OFF   1052672u           // f16 [64][256]
#define CXS_OFF   1085440u           // f32 [64][256]
#define XP_OFF    1150976u           // f16 [Tc*64][1024]

#define SEQ_LDS_BYTES 148480         // 147456 wts + 1024 hx

__device__ __forceinline__ float dot2(unsigned int h, unsigned int w, float acc) {
#if __has_builtin(__builtin_amdgcn_fdot2)
  return __builtin_amdgcn_fdot2(__builtin_bit_cast(f16x2, h),
                                __builtin_bit_cast(f16x2, w), acc, false);
#else
  f16x2 a = __builtin_bit_cast(f16x2, h);
  f16x2 b = __builtin_bit_cast(f16x2, w);
  return acc + (float)a[0] * (float)b[0] + (float)a[1] * (float)b[1];
#endif
}

__device__ __forceinline__ float fast_sigmoid(float x) {
  float e = __expf(-x);
  return __builtin_amdgcn_rcpf(1.0f + e);
}
__device__ __forceinline__ float fast_tanh(float x) {
  x = fminf(fmaxf(x, -15.0f), 15.0f);
  float e = __expf(2.0f * x);
  return (e - 1.0f) * __builtin_amdgcn_rcpf(e + 1.0f);
}

// LDS-only barrier: does NOT drain vmcnt (out-store / Xp prefetch ride across).
__device__ __forceinline__ void lds_barrier() {
  asm volatile("s_waitcnt lgkmcnt(0)\n\ts_barrier" ::: "memory");
}

// ---------------- prep: convert / repack weights ----------------
__global__ void qlstm_prep(const float* __restrict__ Wf, const float* __restrict__ Wi,
                           const float* __restrict__ Wg, const float* __restrict__ Wo,
                           const float* __restrict__ bf_, const float* __restrict__ bi_,
                           const float* __restrict__ bg_, const float* __restrict__ bo_,
                           f16* __restrict__ Wxp, f16* __restrict__ WhV,
                           f16* __restrict__ WhL, float* __restrict__ biasp) {
  int tid = blockIdx.x * 256 + threadIdx.x;
  if (tid < 4 * 512 * 256) {
    int g = tid >> 17;
    int rem = tid & 131071;
    int k = rem >> 8, n = rem & 255;
    const float* W = (g == 0) ? Wf : (g == 1) ? Wi : (g == 2) ? Wg : Wo;
    float v = W[k * 256 + n];
    int j = (g << 8) + n;
    f16 hv = (f16)v;
    if (k < 256) {
      Wxp[((size_t)(k >> 3) * 1024 + j) * 8 + (k & 7)] = hv;
    } else {
      int kk = k - 256;
      if (kk < RV) {
        WhV[(size_t)j * RV + kk] = hv;
      } else {
        int r = kk - RV;
        WhL[((size_t)(r >> 3) * 1024 + j) * 8 + (r & 7)] = hv;
      }
    }
  }
  if (tid < 1024) {
    int g = tid >> 8, n = tid & 255;
    const float* bb = (g == 0) ? bf_ : (g == 1) ? bi_ : (g == 2) ? bg_ : bo_;
    biasp[tid] = bb[n];
  }
}

// ---------------- phase 1: Xp = x @ Wx + bias  (MFMA f16) ----------------
__global__ __launch_bounds__(256) void qlstm_xproj(
    const float* __restrict__ X, const f16* __restrict__ Wxp,
    const float* __restrict__ biasp, f16* __restrict__ Xp) {
  __shared__ f16 As[128][72];
  __shared__ f16 Bs[8 * 128 * 8];

  int tid = threadIdx.x;
  int tm = blockIdx.x, tn = blockIdx.y;
  int wave = tid >> 6, lane = tid & 63;
  int qm = (wave & 1) * 64, qn = (wave >> 1) * 64;
  int lm = lane & 15, lk = lane >> 4;

  f32x4 acc[4][4];
#pragma unroll
  for (int a = 0; a < 4; ++a)
#pragma unroll
    for (int b = 0; b < 4; ++b) acc[a][b] = (f32x4)0.0f;

  for (int k0 = 0; k0 < 256; k0 += 64) {
    {
      int r = tid >> 1, c0 = (tid & 1) * 32;
      const float4* src = (const float4*)(X + (size_t)(tm * 128 + r) * 256 + k0 + c0);
#pragma unroll
      for (int i = 0; i < 8; ++i) {
        float4 v = src[i];
        f16x4 pk = {(f16)v.x, (f16)v.y, (f16)v.z, (f16)v.w};
        *(f16x4*)&As[r][c0 + i * 4] = pk;
      }
    }
    {
#pragma unroll
      for (int it = 0; it < 4; ++it) {
        int idx = it * 256 + tid;
        int kgi = idx >> 7, n = idx & 127;
        ((uint4*)Bs)[idx] =
            *(const uint4*)(Wxp + (((size_t)(k0 >> 3) + kgi) * 1024 + tn * 128 + n) * 8);
      }
    }
    __syncthreads();
#pragma unroll
    for (int ks = 0; ks < 2; ++ks) {
      f16x8 af[4], bfr[4];
#pragma unroll
      for (int mi = 0; mi < 4; ++mi)
        af[mi] = *(const f16x8*)&As[qm + mi * 16 + lm][ks * 32 + lk * 8];
#pragma unroll
      for (int ni = 0; ni < 4; ++ni)
        bfr[ni] = *(const f16x8*)&Bs[(((ks * 4 + lk) * 128) + qn + ni * 16 + lm) * 8];
#pragma unroll
      for (int mi = 0; mi < 4; ++mi)
#pragma unroll
        for (int ni = 0; ni < 4; ++ni)
          acc[mi][ni] = __builtin_amdgcn_mfma_f32_16x16x32_f16(af[mi], bfr[ni],
                                                               acc[mi][ni], 0, 0, 0);
    }
    __syncthreads();
  }
  int m0 = tm * 128 + qm, j0 = tn * 128 + qn;
#pragma unroll
  for (int mi = 0; mi < 4; ++mi)
#pragma unroll
    for (int ni = 0; ni < 4; ++ni) {
      int j = j0 + ni * 16 + lm;
      float bv = biasp[j];
#pragma unroll
      for (int r = 0; r < 4; ++r) {
        int m = m0 + mi * 16 + lk * 4 + r;
        Xp[(size_t)m * 1024 + j] = (f16)(acc[mi][ni][r] + bv);
      }
    }
}

// ---------------- phase 2: sequential LSTM ----------------
// Register chunk c (rows 8c..8c+7): dual accumulators, a/c-alternating issue.
#define RCH(c)                                                                \
  do {                                                                        \
    unsigned s0 = (unsigned)__builtin_amdgcn_readlane((int)hl.x, 2 * (c));    \
    unsigned s1 = (unsigned)__builtin_amdgcn_readlane((int)hl.y, 2 * (c));    \
    unsigned s2 = (unsigned)__builtin_amdgcn_readlane((int)hl.x, 2 * (c) + 1);\
    unsigned s3 = (unsigned)__builtin_amdgcn_readlane((int)hl.y, 2 * (c) + 1);\
    a0 = dot2(s0, wr0[c].x, a0); a1 = dot2(s0, wr1[c].x, a1);                 \
    c0_ = dot2(s1, wr0[c].y, c0_); c1_ = dot2(s1, wr1[c].y, c1_);             \
    a0 = dot2(s2, wr0[c].z, a0); a1 = dot2(s2, wr1[c].z, a1);                 \
    c0_ = dot2(s3, wr0[c].w, c0_); c1_ = dot2(s3, wr1[c].w, c1_);             \
  } while (0)

// Issue LDS chunk c into landing regs (2 cols):
#define LISS(P0, P1, c)                                                       \
  do {                                                                        \
    P0 = wl[(c) * 1024];                                                      \
    P1 = wl[(c) * 1024 + 256];                                                \
  } while (0)

// Consume landed LDS chunk (global chunk index cc = 23 + c):
#define LCONS(P0, P1, cc)                                                     \
  do {                                                                        \
    unsigned s0 = (unsigned)__builtin_amdgcn_readlane((int)hl.x, 2 * (cc));   \
    unsigned s1 = (unsigned)__builtin_amdgcn_readlane((int)hl.y, 2 * (cc));   \
    unsigned s2 = (unsigned)__builtin_amdgcn_readlane((int)hl.x, 2 * (cc) + 1);\
    unsigned s3 = (unsigned)__builtin_amdgcn_readlane((int)hl.y, 2 * (cc) + 1);\
    a0 = dot2(s0, P0.x, a0); a1 = dot2(s0, P1.x, a1);                         \
    c0_ = dot2(s1, P0.y, c0_); c1_ = dot2(s1, P1.y, c1_);                     \
    a0 = dot2(s2, P0.z, a0); a1 = dot2(s2, P1.z, a1);                         \
    c0_ = dot2(s3, P0.w, c0_); c1_ = dot2(s3, P1.w, c1_);                     \
  } while (0)

__global__ __launch_bounds__(512)
__attribute__((amdgpu_waves_per_eu(2, 2))) void qlstm_seq(
    const f16* __restrict__ Xp, const f16* __restrict__ WhV,
    const f16* __restrict__ WhL,
    float* __restrict__ out, f16* __restrict__ hxs, float* __restrict__ cxs,
    float* __restrict__ hxout, float* __restrict__ cxout, int t0, int t1) {
  extern __shared__ char smem[];
  f16* wlds = (f16*)smem;                 // 147456 B: [9][1024][8]
  f16* hxb = (f16*)(smem + 147456);       // [2][256]

  int tid = threadIdx.x;
  int wave = tid >> 6, lane = tid & 63;
  int p = lane >> 5;                      // gate-pair id within the wave
  int h = (wave << 5) + (lane & 31);      // output column this thread serves
  int b = blockIdx.x;
  int j0 = p * 512 + h;                   // p=0: f-col; p=1: g-col
  bool lo = (lane < 32);
  // SIMD = wave&3, so the co-resident pair on a SIMD is {w, w+4}:
  // stagger key must differ within the pair -> (wave>>2)&1.
  bool lds_early = ((wave >> 2) & 1) == 0;

  // stage LDS weights (9216 uint4 over 512 threads)
  {
    const uint4* src = (const uint4*)WhL;
    uint4* dst = (uint4*)wlds;
#pragma unroll
    for (int i = 0; i < 18; ++i) dst[i * 512 + tid] = src[i * 512 + tid];
  }

  // register-resident weights: 2 cols x 23 uint4 = 184 regs
  uint4 wr0[RVC], wr1[RVC];
  {
    const uint4* q0 = (const uint4*)WhV + (size_t)j0 * RVC;
    const uint4* q1 = (const uint4*)WhV + (size_t)(j0 + 256) * RVC;
#pragma unroll
    for (int c = 0; c < RVC; ++c) { wr0[c] = q0[c]; wr1[c] = q1[c]; }
  }

  float cx = 0.0f;
  int par0 = t0 & 1;
  if (t0 == 0) {
    if (lo) hxb[par0 * 256 + h] = (f16)0.0f;
  } else {
    if (lo) hxb[par0 * 256 + h] = hxs[b * 256 + h];
    cx = cxs[b * 256 + h];               // both partner lanes carry cx
  }

  const f16* xpb = Xp + (size_t)b * 1024;
  f16 xa = xpb[j0], xb_ = xpb[j0 + 256];

  const uint4* wl = (const uint4*)wlds + j0;

  __syncthreads();

  float hv = 0.0f;
  for (int t = t0; t < t1; ++t) {
    int par = t & 1;
    // whole hx into the wave: lane l holds hx[4l..4l+4)
    uint2 hl = *(const uint2*)(hxb + par * 256 + lane * 4);

    float a0 = (float)xa, a1 = (float)xb_;
    float c0_ = 0.0f, c1_ = 0.0f;        // secondary accumulators (dep-chain split)

    // prefetch next step's Xp (independent of recurrence; never drained in-loop)
    int tnx = (t + 1 < t1) ? (t + 1 - t0) : (t - t0);
    const f16* xq = Xp + ((size_t)tnx * BATCH + b) * 1024;
    f16 xna = xq[j0], xnb = xq[j0 + 256];

    uint4 A0, A1, B0, B1;               // shared landing regs, both schedules
    if (lds_early) {
      // ---- waves 0-3: r2's exact order — DS interleave early, pure RCH tail ----
      LISS(A0, A1, 0);
      LISS(B0, B1, 1);
      RCH(0); RCH(1);
      LCONS(A0, A1, 23); LISS(A0, A1, 2);
      RCH(2); RCH(3);
      LCONS(B0, B1, 24); LISS(B0, B1, 3);
      RCH(4); RCH(5);
      LCONS(A0, A1, 25); LISS(A0, A1, 4);
      RCH(6); RCH(7);
      LCONS(B0, B1, 26); LISS(B0, B1, 5);
      RCH(8); RCH(9);
      LCONS(A0, A1, 27); LISS(A0, A1, 6);
      RCH(10); RCH(11);
      LCONS(B0, B1, 28); LISS(B0, B1, 7);
      RCH(12); RCH(13);
      LCONS(A0, A1, 29); LISS(A0, A1, 8);
      RCH(14); RCH(15);
      LCONS(B0, B1, 30);
      RCH(16); RCH(17);
      LCONS(A0, A1, 31);
      RCH(18); RCH(19); RCH(20); RCH(21); RCH(22);
    } else {
      // ---- waves 4-7: 13 pure-VGPR chunks first (covering partner's DS phase),
      //      then the same 2-deep DS interleave compressed into the tail ----
      RCH(0); RCH(1); RCH(2); RCH(3);
      RCH(4); RCH(5); RCH(6); RCH(7);
      RCH(8); RCH(9); RCH(10); RCH(11);
      RCH(12);
      LISS(A0, A1, 0);
      LISS(B0, B1, 1);
      RCH(13);
      LCONS(A0, A1, 23); LISS(A0, A1, 2);
      RCH(14);
      LCONS(B0, B1, 24); LISS(B0, B1, 3);
      RCH(15);
      LCONS(A0, A1, 25); LISS(A0, A1, 4);
      RCH(16);
      LCONS(B0, B1, 26); LISS(B0, B1, 5);
      RCH(17);
      LCONS(A0, A1, 27); LISS(A0, A1, 6);
      RCH(18);
      LCONS(B0, B1, 28); LISS(B0, B1, 7);
      RCH(19);
      LCONS(A0, A1, 29); LISS(A0, A1, 8);
      RCH(20);
      LCONS(B0, B1, 30);
      RCH(21);
      LCONS(A0, A1, 31);
      RCH(22);
    }

    a0 += c0_;
    a1 += c1_;

    // in-wave gate exchange: partner lane (lane^32) has the other 2 gates
    float r0 = __shfl_xor(a0, 32, 64);
    float r1 = __shfl_xor(a1, 32, 64);
    float pf = lo ? a0 : r0;
    float pi = lo ? a1 : r1;
    float pg = lo ? r0 : a0;
    float po = lo ? r1 : a1;

    float vf = fast_sigmoid(pf);
    float vi = fast_sigmoid(pi);
    float vg = fast_tanh(pg);
    float vo = fast_sigmoid(po);
    cx = fmaf(vf, cx, vi * vg);           // both partner lanes keep cx
    hv = vo * fast_tanh(cx);
    if (lo) {
      out[((size_t)t * BATCH + b) * 256 + h] = hv;
      hxb[(par ^ 1) * 256 + h] = (f16)hv;
    }
    lds_barrier();                        // lgkmcnt(0) + s_barrier, NO vmcnt drain

    xa = xna; xb_ = xnb;
  }

  if (lo) {
    hxs[b * 256 + h] = (f16)hv;
    cxs[b * 256 + h] = cx;
    if (t1 == SEQ) {
      hxout[b * 256 + h] = hv;
      cxout[b * 256 + h] = cx;
    }
  }
}

extern "C" void kernel_launch(void* const* d_in, const int* in_sizes, int n_in,
                              void* d_out, int out_size, void* d_ws, size_t ws_size,
                              hipStream_t stream) {
  const float* X  = (const float*)d_in[0];
  const float* Wf = (const float*)d_in[1]; const float* bf_ = (const float*)d_in[2];
  const float* Wi = (const float*)d_in[3]; const float* bi_ = (const float*)d_in[4];
  const float* Wg = (const float*)d_in[5]; const float* bg_ = (const float*)d_in[6];
  const float* Wo = (const float*)d_in[7]; const float* bo_ = (const float*)d_in[8];
  float* out = (float*)d_out;

  char* ws = (char*)d_ws;
  f16*   Wxp   = (f16*)(ws + WXP_OFF);
  f16*   WhV   = (f16*)(ws + WHV_OFF);
  f16*   WhL   = (f16*)(ws + WHL_OFF);
  float* biasp = (float*)(ws + BIAS_OFF);
  f16*   hxs   = (f16*)(ws + HXS_OFF);
  float* cxs   = (float*)(ws + CXS_OFF);
  f16*   Xp    = (f16*)(ws + XP_OFF);

  size_t avail = (ws_size > XP_OFF) ? (ws_size - XP_OFF) : 0;
  int Tc = SEQ;
  while (Tc > 2 && (size_t)Tc * BATCH * NCOL * 2 > avail) Tc >>= 1;

  qlstm_prep<<<2048, 256, 0, stream>>>(Wf, Wi, Wg, Wo, bf_, bi_, bg_, bo_,
                                       Wxp, WhV, WhL, biasp);

  (void)hipFuncSetAttribute((const void*)qlstm_seq,
                            hipFuncAttributeMaxDynamicSharedMemorySize,
                            SEQ_LDS_BYTES);

  float* hxout = out + (size_t)SEQ * BATCH * DH;
  float* cxout = hxout + BATCH * DH;

  for (int t0 = 0; t0 < SEQ; t0 += Tc) {
    dim3 g1(Tc * BATCH / 128, NCOL / 128);
    qlstm_xproj<<<g1, 256, 0, stream>>>(X + (size_t)t0 * BATCH * DIN, Wxp, biasp, Xp);
    qlstm_seq<<<BATCH, 512, SEQ_LDS_BYTES, stream>>>(Xp, WhV, WhL, out, hxs, cxs,
                                                     hxout, cxout, t0, t0 + Tc);
  }
}

// Round 6
// 1877.768 us; speedup vs baseline: 7.6609x; 1.1145x over previous
//
#include <hip/hip_runtime.h>
#include <hip/hip_bf16.h>

// QLSTM: SEQ=1024, B=64, D_IN=256, D_H=256, fp32 in/out.
// Phase 1: Xp = x @ Wx + bias  (f16 MFMA GEMM) — unchanged.
// Phase 2: 64 WGs (1/batch), 512 thr, 8 waves, 2/SIMD, ONE lds_barrier/step.
//   ENGINE SWAP (r5 lesson): VALU-dot2 needs >=352KB weights in regs (LDS caps at
//   ~150KB) -> they live in AGPRs -> v_accvgpr_read per use = ~450 extra VALU/step
//   (measured: 81% active-CU VALUBusy, VGPR_Count=128). MFMA reads AGPRs NATIVELY.
//   mfma_f32_16x16x32_f16 with M=1: A row0 = hx (broadcast ds_read_b128, rows 1-15
//   garbage, never read); B = weight tiles; D row0 (lanes 0-15, reg 0) = gate pre-acts.
//   Wave w owns cols {g*256 + 32w + 16s + c}: 8 N-tiles (g,s), so f/i/g/o for one h
//   sit in the SAME lane across 4 accs -> activation per-lane, no gate exchange.
//   Weights/wave = 64 tiles (8 N x 8 K): 45 resident in regs (180 VGPR/AGPR),
//   19 streamed from LDS (8 waves x 19 KB = 152 KB), 2-deep landing dbuf.
//   Per-step: 8 MFMA x 8 kt = 64 MFMA, 19 W-reads + 8 A-reads + 2 h-writes DS.
// Tile fragment layouts verified against the proven xproj kernel (A: row=lane&15,
//   k=(lane>>4)*8+j; B: col=lane&15, same k; D: col=lane&15, row=(lane>>4)*4+reg).

typedef _Float16 f16;
typedef _Float16 f16x4 __attribute__((ext_vector_type(4)));
typedef _Float16 f16x8 __attribute__((ext_vector_type(8)));
typedef float f32x4 __attribute__((ext_vector_type(4)));

#define SEQ 1024
#define BATCH 64
#define DIN 256
#define DH 256
#define NCOL 1024
#define NRES 45              // register-resident weight tiles per wave
#define NSTR 19              // LDS-streamed weight tiles per wave

// ---- ws layout (bytes) ----
#define WXP_OFF   0u                 // f16 [32][1024][8]           = 524288
#define WHR_OFF   524288u            // uint4 [8][45][64] (f16 x8)  = 368640
#define WHL_OFF   892928u            // uint4 [8][19][64]           = 155648
#define BIAS_OFF  1048576u           // f32 [1024]
#define HXS_OFF   1052672u           // f16 [64][256]
#define CXS_OFF   1085440u           // f32 [64][256]
#define XP_OFF    1150976u           // f16 [Tc*64][1024]

#define WLDS_BYTES 155648            // 8 waves * 19 tiles * 1024 B
#define SEQ_LDS_BYTES 156672         // + hxb [2][256] f16

__device__ __forceinline__ float fast_sigmoid(float x) {
  float e = __expf(-x);
  return __builtin_amdgcn_rcpf(1.0f + e);
}
__device__ __forceinline__ float fast_tanh(float x) {
  x = fminf(fmaxf(x, -15.0f), 15.0f);
  float e = __expf(2.0f * x);
  return (e - 1.0f) * __builtin_amdgcn_rcpf(e + 1.0f);
}

// LDS-only barrier: no vmcnt drain (out-stores / Xp loads ride across).
__device__ __forceinline__ void lds_barrier() {
  asm volatile("s_waitcnt lgkmcnt(0)\n\ts_barrier" ::: "memory");
}

__device__ __forceinline__ f32x4 MF(f16x8 a, f16x8 b, f32x4 c) {
  return __builtin_amdgcn_mfma_f32_16x16x32_f16(a, b, c, 0, 0, 0);
}
#define RB(u) __builtin_bit_cast(f16x8, (u))

// ---------------- prep: convert / repack weights ----------------
__global__ void qlstm_prep(const float* __restrict__ Wf, const float* __restrict__ Wi,
                           const float* __restrict__ Wg, const float* __restrict__ Wo,
                           const float* __restrict__ bf_, const float* __restrict__ bi_,
                           const float* __restrict__ bg_, const float* __restrict__ bo_,
                           f16* __restrict__ Wxp, f16* __restrict__ WhR,
                           f16* __restrict__ WhL, float* __restrict__ biasp) {
  int tid = blockIdx.x * 256 + threadIdx.x;
  if (tid < 4 * 512 * 256) {
    int g = tid >> 17;
    int rem = tid & 131071;
    int k = rem >> 8, n = rem & 255;
    const float* W = (g == 0) ? Wf : (g == 1) ? Wi : (g == 2) ? Wg : Wo;
    float v = W[k * 256 + n];
    f16 hv = (f16)v;
    if (k < 256) {
      int j = (g << 8) + n;
      Wxp[((size_t)(k >> 3) * 1024 + j) * 8 + (k & 7)] = hv;
    } else {
      int kk = k - 256;                 // hx-row 0..255
      int w = n >> 5, c = n & 15, sh = (n >> 4) & 1;
      int nt = g * 2 + sh;              // N-tile 0..7 within wave w
      int kt = kk >> 5;                 // K-tile 0..7
      int lane = ((kk >> 3) & 3) * 16 + c;
      int j = kk & 7;
      bool res = (nt < 5) || (nt == 5 && kt < 5);
      if (res) {
        int r = (nt < 5) ? kt * 5 + nt : 40 + kt;
        WhR[((size_t)(w * NRES + r) * 64 + lane) * 8 + j] = hv;
      } else {
        int s = (nt == 5) ? kt - 5 : ((nt == 6) ? 3 + kt : 11 + kt);
        WhL[((size_t)(w * NSTR + s) * 64 + lane) * 8 + j] = hv;
      }
    }
  }
  if (tid < 1024) {
    int g = tid >> 8, n = tid & 255;
    const float* bb = (g == 0) ? bf_ : (g == 1) ? bi_ : (g == 2) ? bg_ : bo_;
    biasp[tid] = bb[n];
  }
}

// ---------------- phase 1: Xp = x @ Wx + bias  (MFMA f16) ----------------
__global__ __launch_bounds__(256) void qlstm_xproj(
    const float* __restrict__ X, const f16* __restrict__ Wxp,
    const float* __restrict__ biasp, f16* __restrict__ Xp) {
  __shared__ f16 As[128][72];
  __shared__ f16 Bs[8 * 128 * 8];

  int tid = threadIdx.x;
  int tm = blockIdx.x, tn = blockIdx.y;
  int wave = tid >> 6, lane = tid & 63;
  int qm = (wave & 1) * 64, qn = (wave >> 1) * 64;
  int lm = lane & 15, lk = lane >> 4;

  f32x4 acc[4][4];
#pragma unroll
  for (int a = 0; a < 4; ++a)
#pragma unroll
    for (int b = 0; b < 4; ++b) acc[a][b] = (f32x4)0.0f;

  for (int k0 = 0; k0 < 256; k0 += 64) {
    {
      int r = tid >> 1, c0 = (tid & 1) * 32;
      const float4* src = (const float4*)(X + (size_t)(tm * 128 + r) * 256 + k0 + c0);
#pragma unroll
      for (int i = 0; i < 8; ++i) {
        float4 v = src[i];
        f16x4 pk = {(f16)v.x, (f16)v.y, (f16)v.z, (f16)v.w};
        *(f16x4*)&As[r][c0 + i * 4] = pk;
      }
    }
    {
#pragma unroll
      for (int it = 0; it < 4; ++it) {
        int idx = it * 256 + tid;
        int kgi = idx >> 7, n = idx & 127;
        ((uint4*)Bs)[idx] =
            *(const uint4*)(Wxp + (((size_t)(k0 >> 3) + kgi) * 1024 + tn * 128 + n) * 8);
      }
    }
    __syncthreads();
#pragma unroll
    for (int ks = 0; ks < 2; ++ks) {
      f16x8 af[4], bfr[4];
#pragma unroll
      for (int mi = 0; mi < 4; ++mi)
        af[mi] = *(const f16x8*)&As[qm + mi * 16 + lm][ks * 32 + lk * 8];
#pragma unroll
      for (int ni = 0; ni < 4; ++ni)
        bfr[ni] = *(const f16x8*)&Bs[(((ks * 4 + lk) * 128) + qn + ni * 16 + lm) * 8];
#pragma unroll
      for (int mi = 0; mi < 4; ++mi)
#pragma unroll
        for (int ni = 0; ni < 4; ++ni)
          acc[mi][ni] = __builtin_amdgcn_mfma_f32_16x16x32_f16(af[mi], bfr[ni],
                                                               acc[mi][ni], 0, 0, 0);
    }
    __syncthreads();
  }
  int m0 = tm * 128 + qm, j0 = tn * 128 + qn;
#pragma unroll
  for (int mi = 0; mi < 4; ++mi)
#pragma unroll
    for (int ni = 0; ni < 4; ++ni) {
      int j = j0 + ni * 16 + lm;
      float bv = biasp[j];
#pragma unroll
      for (int r = 0; r < 4; ++r) {
        int m = m0 + mi * 16 + lk * 4 + r;
        Xp[(size_t)m * 1024 + j] = (f16)(acc[mi][ni][r] + bv);
      }
    }
}

// ---------------- phase 2: sequential LSTM via M=1 MFMA ----------------
// A-fragment: row = lane&15 (all rows fed the same hx -> row0 correct, rest garbage),
// k = kt*32 + (lane>>4)*8 + j. Broadcast read: uniform addr per 16-lane group.
#define ARD(kt) \
  __builtin_bit_cast(f16x8, *(const uint4*)(hxp + (kt) * 32 + ((lane >> 4) << 3)))

__global__ __launch_bounds__(512)
__attribute__((amdgpu_waves_per_eu(2, 2))) void qlstm_seq(
    const f16* __restrict__ Xp, const uint4* __restrict__ WhR,
    const uint4* __restrict__ WhL,
    float* __restrict__ out, f16* __restrict__ hxs, float* __restrict__ cxs,
    float* __restrict__ hxout, float* __restrict__ cxout, int t0, int t1) {
  extern __shared__ char smem[];
  uint4* wlds = (uint4*)smem;                  // [8][19][64] uint4 (1:1 with WhL)
  f16* hxb = (f16*)(smem + WLDS_BYTES);        // [2][256]

  int tid = threadIdx.x;
  int w = tid >> 6, lane = tid & 63;
  int c = lane & 15;
  int b = blockIdx.x;
  int h0 = (w << 5) + c, h1 = h0 + 16;

  // stage streamed weight tiles (flat 1:1 copy, 19 uint4/thread)
#pragma unroll
  for (int i = 0; i < NSTR; ++i) wlds[i * 512 + tid] = WhL[i * 512 + tid];

  // register-resident weight tiles: 45 x uint4 = 180 regs (VGPR/AGPR; MFMA reads both)
  uint4 wres[NRES];
  {
    const uint4* q = WhR + (size_t)w * NRES * 64 + lane;
#pragma unroll
    for (int r = 0; r < NRES; ++r) wres[r] = q[r * 64];
  }

  unsigned* hx32 = (unsigned*)hxb;
  int par0 = t0 & 1;
  if (tid < 128)
    hx32[par0 * 128 + tid] = (t0 == 0) ? 0u : ((const unsigned*)hxs)[b * 128 + tid];
  float cx0 = 0.0f, cx1 = 0.0f;
  if (t0 != 0) { cx0 = cxs[b * 256 + h0]; cx1 = cxs[b * 256 + h1]; }

  const uint4* wbase = wlds + (size_t)w * (NSTR * 64) + lane;

  __syncthreads();

  float hv0 = 0.0f, hv1 = 0.0f;
  for (int t = t0; t < t1; ++t) {
    int par = t & 1, parn = par ^ 1;
    const f16* hxp = hxb + par * 256;

    // Xp for this step (8 scalar f16); issued early, consumed after the K-loop.
    const f16* xq = Xp + ((size_t)(t - t0) * BATCH + b) * NCOL;
    f16 xv0 = xq[h0],       xv1 = xq[h1];
    f16 xv2 = xq[256 + h0], xv3 = xq[256 + h1];
    f16 xv4 = xq[512 + h0], xv5 = xq[512 + h1];
    f16 xv6 = xq[768 + h0], xv7 = xq[768 + h1];

    f32x4 q0{}, q1{}, q2{}, q3{}, q4{}, q5{}, q6{}, q7{};
    uint4 La{}, Lb{}, Lc{}, Ma{}, Mb{}, Mc{};

    // prologue: A(kt0) + kt0's streamed tiles
    f16x8 Ac = ARD(0);
    La = wbase[3 * 64]; Lb = wbase[11 * 64];

    // kt0: consume L, issue M(kt1)
    { f16x8 An = ARD(1); Ma = wbase[4 * 64]; Mb = wbase[12 * 64];
      q0 = MF(Ac, RB(wres[0]), q0); q1 = MF(Ac, RB(wres[1]), q1);
      q2 = MF(Ac, RB(wres[2]), q2); q3 = MF(Ac, RB(wres[3]), q3);
      q4 = MF(Ac, RB(wres[4]), q4); q5 = MF(Ac, RB(wres[40]), q5);
      q6 = MF(Ac, RB(La), q6);      q7 = MF(Ac, RB(Lb), q7); Ac = An; }
    // kt1: consume M, issue L(kt2)
    { f16x8 An = ARD(2); La = wbase[5 * 64]; Lb = wbase[13 * 64];
      q0 = MF(Ac, RB(wres[5]), q0); q1 = MF(Ac, RB(wres[6]), q1);
      q2 = MF(Ac, RB(wres[7]), q2); q3 = MF(Ac, RB(wres[8]), q3);
      q4 = MF(Ac, RB(wres[9]), q4); q5 = MF(Ac, RB(wres[41]), q5);
      q6 = MF(Ac, RB(Ma), q6);      q7 = MF(Ac, RB(Mb), q7); Ac = An; }
    // kt2
    { f16x8 An = ARD(3); Ma = wbase[6 * 64]; Mb = wbase[14 * 64];
      q0 = MF(Ac, RB(wres[10]), q0); q1 = MF(Ac, RB(wres[11]), q1);
      q2 = MF(Ac, RB(wres[12]), q2); q3 = MF(Ac, RB(wres[13]), q3);
      q4 = MF(Ac, RB(wres[14]), q4); q5 = MF(Ac, RB(wres[42]), q5);
      q6 = MF(Ac, RB(La), q6);       q7 = MF(Ac, RB(Lb), q7); Ac = An; }
    // kt3
    { f16x8 An = ARD(4); La = wbase[7 * 64]; Lb = wbase[15 * 64];
      q0 = MF(Ac, RB(wres[15]), q0); q1 = MF(Ac, RB(wres[16]), q1);
      q2 = MF(Ac, RB(wres[17]), q2); q3 = MF(Ac, RB(wres[18]), q3);
      q4 = MF(Ac, RB(wres[19]), q4); q5 = MF(Ac, RB(wres[43]), q5);
      q6 = MF(Ac, RB(Ma), q6);       q7 = MF(Ac, RB(Mb), q7); Ac = An; }
    // kt4: issue M(kt5) incl. first streamed nt5 tile (s0)
    { f16x8 An = ARD(5); Ma = wbase[8 * 64]; Mb = wbase[16 * 64]; Mc = wbase[0];
      q0 = MF(Ac, RB(wres[20]), q0); q1 = MF(Ac, RB(wres[21]), q1);
      q2 = MF(Ac, RB(wres[22]), q2); q3 = MF(Ac, RB(wres[23]), q3);
      q4 = MF(Ac, RB(wres[24]), q4); q5 = MF(Ac, RB(wres[44]), q5);
      q6 = MF(Ac, RB(La), q6);       q7 = MF(Ac, RB(Lb), q7); Ac = An; }
    // kt5: consume M(a,b,c), issue L(kt6)
    { f16x8 An = ARD(6); La = wbase[9 * 64]; Lb = wbase[17 * 64]; Lc = wbase[1 * 64];
      q0 = MF(Ac, RB(wres[25]), q0); q1 = MF(Ac, RB(wres[26]), q1);
      q2 = MF(Ac, RB(wres[27]), q2); q3 = MF(Ac, RB(wres[28]), q3);
      q4 = MF(Ac, RB(wres[29]), q4); q5 = MF(Ac, RB(Mc), q5);
      q6 = MF(Ac, RB(Ma), q6);       q7 = MF(Ac, RB(Mb), q7); Ac = An; }
    // kt6: consume L(a,b,c), issue M(kt7)
    { f16x8 An = ARD(7); Ma = wbase[10 * 64]; Mb = wbase[18 * 64]; Mc = wbase[2 * 64];
      q0 = MF(Ac, RB(wres[30]), q0); q1 = MF(Ac, RB(wres[31]), q1);
      q2 = MF(Ac, RB(wres[32]), q2); q3 = MF(Ac, RB(wres[33]), q3);
      q4 = MF(Ac, RB(wres[34]), q4); q5 = MF(Ac, RB(Lc), q5);
      q6 = MF(Ac, RB(La), q6);       q7 = MF(Ac, RB(Lb), q7); Ac = An; }
    // kt7: consume M(a,b,c)
    { q0 = MF(Ac, RB(wres[35]), q0); q1 = MF(Ac, RB(wres[36]), q1);
      q2 = MF(Ac, RB(wres[37]), q2); q3 = MF(Ac, RB(wres[38]), q3);
      q4 = MF(Ac, RB(wres[39]), q4); q5 = MF(Ac, RB(Mc), q5);
      q6 = MF(Ac, RB(Ma), q6);       q7 = MF(Ac, RB(Mb), q7); }

    // D row 0 (reg 0) = pre-activations for lanes 0-15; other lanes garbage.
    float p0 = q0[0] + (float)xv0, p1 = q1[0] + (float)xv1;
    float p2 = q2[0] + (float)xv2, p3 = q3[0] + (float)xv3;
    float p4 = q4[0] + (float)xv4, p5 = q5[0] + (float)xv5;
    float p6 = q6[0] + (float)xv6, p7 = q7[0] + (float)xv7;

    // nt = gate*2 + s:  s0 -> {p0,p2,p4,p6} = {f,i,g,o};  s1 -> {p1,p3,p5,p7}
    float vf0 = fast_sigmoid(p0), vi0 = fast_sigmoid(p2);
    float vg0 = fast_tanh(p4),    vo0 = fast_sigmoid(p6);
    float vf1 = fast_sigmoid(p1), vi1 = fast_sigmoid(p3);
    float vg1 = fast_tanh(p5),    vo1 = fast_sigmoid(p7);
    cx0 = fmaf(vf0, cx0, vi0 * vg0); hv0 = vo0 * fast_tanh(cx0);
    cx1 = fmaf(vf1, cx1, vi1 * vg1); hv1 = vo1 * fast_tanh(cx1);

    if (lane < 16) {
      float* op = out + ((size_t)t * BATCH + b) * 256;
      op[h0] = hv0; op[h1] = hv1;
      f16* hw = hxb + parn * 256;
      hw[h0] = (f16)hv0; hw[h1] = (f16)hv1;
    }
    lds_barrier();                       // lgkmcnt(0)+s_barrier, no vmcnt drain
  }

  if (lane < 16) {
    hxs[b * 256 + h0] = (f16)hv0; hxs[b * 256 + h1] = (f16)hv1;
    cxs[b * 256 + h0] = cx0;      cxs[b * 256 + h1] = cx1;
    if (t1 == SEQ) {
      hxout[b * 256 + h0] = hv0; hxout[b * 256 + h1] = hv1;
      cxout[b * 256 + h0] = cx0; cxout[b * 256 + h1] = cx1;
    }
  }
}

extern "C" void kernel_launch(void* const* d_in, const int* in_sizes, int n_in,
                              void* d_out, int out_size, void* d_ws, size_t ws_size,
                              hipStream_t stream) {
  const float* X  = (const float*)d_in[0];
  const float* Wf = (const float*)d_in[1]; const float* bf_ = (const float*)d_in[2];
  const float* Wi = (const float*)d_in[3]; const float* bi_ = (const float*)d_in[4];
  const float* Wg = (const float*)d_in[5]; const float* bg_ = (const float*)d_in[6];
  const float* Wo = (const float*)d_in[7]; const float* bo_ = (const float*)d_in[8];
  float* out = (float*)d_out;

  char* ws = (char*)d_ws;
  f16*   Wxp   = (f16*)(ws + WXP_OFF);
  f16*   WhR   = (f16*)(ws + WHR_OFF);
  f16*   WhL   = (f16*)(ws + WHL_OFF);
  float* biasp = (float*)(ws + BIAS_OFF);
  f16*   hxs   = (f16*)(ws + HXS_OFF);
  float* cxs   = (float*)(ws + CXS_OFF);
  f16*   Xp    = (f16*)(ws + XP_OFF);

  size_t avail = (ws_size > XP_OFF) ? (ws_size - XP_OFF) : 0;
  int Tc = SEQ;
  while (Tc > 2 && (size_t)Tc * BATCH * NCOL * 2 > avail) Tc >>= 1;

  qlstm_prep<<<2048, 256, 0, stream>>>(Wf, Wi, Wg, Wo, bf_, bi_, bg_, bo_,
                                       Wxp, WhR, WhL, biasp);

  (void)hipFuncSetAttribute((const void*)qlstm_seq,
                            hipFuncAttributeMaxDynamicSharedMemorySize,
                            SEQ_LDS_BYTES);

  float* hxout = out + (size_t)SEQ * BATCH * DH;
  float* cxout = hxout + BATCH * DH;

  for (int t0 = 0; t0 < SEQ; t0 += Tc) {
    dim3 g1(Tc * BATCH / 128, NCOL / 128);
    qlstm_xproj<<<g1, 256, 0, stream>>>(X + (size_t)t0 * BATCH * DIN, Wxp, biasp, Xp);
    qlstm_seq<<<BATCH, 512, SEQ_LDS_BYTES, stream>>>(
        Xp, (const uint4*)WhR, (const uint4*)WhL, out, hxs, cxs,
        hxout, cxout, t0, t0 + Tc);
  }
}